// Round 11
// baseline (258.284 us; speedup 1.0000x reference)
//
#include <hip/hip_runtime.h>

#define TT 128
#define NN 512
#define DH 64
#define EE 8192
#define LOB (18 * 8 * 64)   // uint4 count of hi-weight fragments

typedef __bf16 bf16x8 __attribute__((ext_vector_type(8)));
typedef float f32x4 __attribute__((ext_vector_type(4)));

struct US8 { unsigned short u[8]; };
struct Frag { bf16x8 hi, lo; };

static __device__ __forceinline__ unsigned short f2bf(float x) {
    union { float f; unsigned u; } c; c.f = x;
    unsigned r = (c.u + 0x7FFFu + ((c.u >> 16) & 1u)) >> 16;   // RNE
    return (unsigned short)r;
}
static __device__ __forceinline__ float bf2f(unsigned short b) {
    union { unsigned u; float f; } c; c.u = ((unsigned)b) << 16;
    return c.f;
}
static __device__ __forceinline__ float silu_acc(float a, float b, float acc) {
    float x = a + b;
    float e = __expf(-x);
    return fmaf(x, __builtin_amdgcn_rcpf(1.0f + e), acc);
}
static __device__ __forceinline__ float silu_f(float x) {
    float e = __expf(-x);
    return x * __builtin_amdgcn_rcpf(1.0f + e);
}
static __device__ __forceinline__ Frag split8(const float* v) {
    Frag f;
    #pragma unroll
    for (int i = 0; i < 8; ++i) {
        __bf16 hb = (__bf16)v[i];
        f.hi[i] = hb;
        f.lo[i] = (__bf16)(v[i] - (float)hb);
    }
    return f;
}
static __device__ __forceinline__ f32x4 mmac(bf16x8 a, uint4 bw, f32x4 c) {
    return __builtin_amdgcn_mfma_f32_16x16x32_bf16(
        a, __builtin_bit_cast(bf16x8, bw), c, 0, 0, 0);
}
static __device__ __forceinline__ f32x4 mm3(Frag a, uint4 wh, uint4 wl, f32x4 c) {
    c = mmac(a.hi, wh, c);
    c = mmac(a.lo, wh, c);
    c = mmac(a.hi, wl, c);
    return c;
}

// ---- fused setup (unchanged from round 10) ----
__global__ __launch_bounds__(512) void setup_kernel(
    const int* __restrict__ ei,
    const float* __restrict__ msg1_w, const float* __restrict__ msg2_w,
    const float* __restrict__ upd1_w, const float* __restrict__ upd2_w,
    const float* __restrict__ enc_w, const float* __restrict__ enc_b,
    const float* __restrict__ msg1_b,
    uint4* __restrict__ pack,
    int* __restrict__ counts, int* __restrict__ offsets,
    int* __restrict__ ssrc,
    float* __restrict__ E1s, float* __restrict__ E1d,
    float* __restrict__ e0sum) {
    int b = blockIdx.x;
    if (b < 18) {
        int l = b / 6, bi = b % 6;
        const float* W;
        if (bi == 0)      W = msg1_w + (size_t)l * 128 * 64;
        else if (bi == 1) W = msg1_w + (size_t)l * 128 * 64 + 64 * 64;
        else if (bi == 2) W = msg2_w + (size_t)l * 64 * 64;
        else if (bi == 3) W = upd1_w + (size_t)l * 128 * 64;
        else if (bi == 4) W = upd1_w + (size_t)l * 128 * 64 + 64 * 64;
        else              W = upd2_w + (size_t)l * 64 * 64;
        int lane = threadIdx.x & 63;
        int sub  = threadIdx.x >> 6;
        int nt = sub >> 1, kc = sub & 1;
        US8 oh, ol;
        #pragma unroll
        for (int i = 0; i < 8; ++i) {
            int k = kc * 32 + (lane >> 4) * 8 + i;
            int col = nt * 16 + (lane & 15);
            float w = W[k * 64 + col];
            unsigned short hu = f2bf(w);
            oh.u[i] = hu;
            ol.u[i] = f2bf(w - bf2f(hu));
        }
        size_t fi = ((size_t)b * 8 + sub) * 64 + lane;
        pack[fi]       = __builtin_bit_cast(uint4, oh);
        pack[LOB + fi] = __builtin_bit_cast(uint4, ol);
        return;
    }
    if (b == 18) {
        __shared__ int cnt[NN];
        __shared__ int tmp[NN];
        __shared__ int cur[NN];
        int i = threadIdx.x;
        cnt[i] = 0;
        __syncthreads();
        #pragma unroll
        for (int r = 0; r < EE / 512; ++r)
            atomicAdd(&cnt[ei[EE + r * 512 + i]], 1);
        __syncthreads();
        int c = cnt[i];
        tmp[i] = c;
        __syncthreads();
        for (int off = 1; off < NN; off <<= 1) {
            int v = (i >= off) ? tmp[i - off] : 0;
            __syncthreads();
            tmp[i] += v;
            __syncthreads();
        }
        counts[i] = c;
        offsets[i + 1] = tmp[i];
        if (i == 0) offsets[0] = 0;
        cur[i] = tmp[i] - c;
        __syncthreads();
        #pragma unroll
        for (int r = 0; r < EE / 512; ++r) {
            int e = r * 512 + i;
            int dst = ei[EE + e];
            int pos = atomicAdd(&cur[dst], 1);
            ssrc[pos] = ei[e];
        }
        return;
    }
    if (b < 83) {
        int nn = (b - 19) * 8 + (threadIdx.x >> 6);
        int d  = threadIdx.x & 63;
        float s = 0.f, dd = msg1_b[d];
        #pragma unroll 8
        for (int k = 0; k < 64; ++k) {
            float c = enc_w[(1 + nn) * 64 + k] + enc_b[k];
            s  = fmaf(c, msg1_w[k * 64 + d], s);
            dd = fmaf(c, msg1_w[(64 + k) * 64 + d], dd);
        }
        E1s[nn * 64 + d] = s;
        E1d[nn * 64 + d] = dd;
        return;
    }
    if (threadIdx.x < 64) {
        int d = threadIdx.x;
        float s = 0.f, dd = 0.f;
        #pragma unroll 8
        for (int k = 0; k < 64; ++k) {
            float a = enc_w[k];
            s  = fmaf(a, msg1_w[k * 64 + d], s);
            dd = fmaf(a, msg1_w[(64 + k) * 64 + d], dd);
        }
        e0sum[d] = s + dd;
    }
}

// ---- fused layer: block = 16 rows, 4 waves ----
// Phase A: each wave aggregates 4 rows into LDS (AG) + stages h rows (HH).
// Phase B: update MLP MFMAs split across waves by output quadrant (w = nt).
__global__ __launch_bounds__(256) void layer_kernel(
    const float* __restrict__ t, const float* __restrict__ enc_w,
    const float* __restrict__ enc_b, const float* __restrict__ e0sum,
    const float* __restrict__ E1s, const float* __restrict__ E1d,
    float* __restrict__ h, const float* __restrict__ hs_in,
    float* __restrict__ hs_out, float* __restrict__ hd,
    const int* __restrict__ counts, const int* __restrict__ offsets,
    const int* __restrict__ ssrc, const uint4* __restrict__ pack, int l,
    const float* __restrict__ b2, const float* __restrict__ ub1,
    const float* __restrict__ ub2, const float* __restrict__ b1n,
    const float* __restrict__ ro_w, const float* __restrict__ ro_b,
    float* __restrict__ out, int first, int last) {
    __shared__ float AG[16 * 68];   // aggpre rows; reused as z-tile
    __shared__ float HH[16 * 68];   // h rows -> hn rows
    __shared__ float ST[16 * 68];   // stage-1 output (agg)
    int lane = threadIdx.x & 63;
    int w = threadIdx.x >> 6;
    int bid = blockIdx.x;
    int xcd = bid & 7;
    int idx = bid >> 3;                  // 0..511
    int tt  = xcd * 16 + (idx >> 5);     // 16 tt per XCD
    int grp = idx & 31;                  // 16-row group within tt
    int rowbase = tt * NN + grp * 16;
    int nbase = grp * 16;
    int arow = lane & 15, kgrp = lane >> 4, k0 = kgrp * 8;
    float tv = t[tt];

    // ---- phase A ----
    {
        int eg = lane >> 4;                 // edge slot 0..3
        int chb = (lane & 15) * 4;          // float index of lane's float4
        int ch4 = chb * 4;                  // byte offset
        const char* gb = first ? (const char*)E1s
                               : (const char*)(hs_in + (size_t)tt * NN * DH);
        for (int j = w * 4; j < w * 4 + 4; ++j) {
            int nn = nbase + j;
            float4 base;
            if (first) {
                float4 e0 = *(const float4*)(e0sum + chb);
                float4 ed = *(const float4*)(E1d + nn * DH + chb);
                base = make_float4(fmaf(tv, e0.x, ed.x), fmaf(tv, e0.y, ed.y),
                                   fmaf(tv, e0.z, ed.z), fmaf(tv, e0.w, ed.w));
            } else {
                base = *(const float4*)(hd + ((size_t)tt * NN + nn) * DH + chb);
            }
            int beg = offsets[nn], end = offsets[nn + 1];
            float4 acc = make_float4(0.f, 0.f, 0.f, 0.f);
            int i = beg + eg;
            for (; i + 4 < end; i += 8) {
                int s0 = ssrc[i] << 8;
                int s1 = ssrc[i + 4] << 8;
                float4 v0 = *(const float4*)(gb + s0 + ch4);
                float4 v1 = *(const float4*)(gb + s1 + ch4);
                acc.x = silu_acc(v0.x, base.x, acc.x);
                acc.y = silu_acc(v0.y, base.y, acc.y);
                acc.z = silu_acc(v0.z, base.z, acc.z);
                acc.w = silu_acc(v0.w, base.w, acc.w);
                acc.x = silu_acc(v1.x, base.x, acc.x);
                acc.y = silu_acc(v1.y, base.y, acc.y);
                acc.z = silu_acc(v1.z, base.z, acc.z);
                acc.w = silu_acc(v1.w, base.w, acc.w);
            }
            if (i < end) {
                int s0 = ssrc[i] << 8;
                float4 v0 = *(const float4*)(gb + s0 + ch4);
                acc.x = silu_acc(v0.x, base.x, acc.x);
                acc.y = silu_acc(v0.y, base.y, acc.y);
                acc.z = silu_acc(v0.z, base.z, acc.z);
                acc.w = silu_acc(v0.w, base.w, acc.w);
            }
            acc.x += __shfl_xor(acc.x, 16); acc.x += __shfl_xor(acc.x, 32);
            acc.y += __shfl_xor(acc.y, 16); acc.y += __shfl_xor(acc.y, 32);
            acc.z += __shfl_xor(acc.z, 16); acc.z += __shfl_xor(acc.z, 32);
            acc.w += __shfl_xor(acc.w, 16); acc.w += __shfl_xor(acc.w, 32);
            if (eg == 0) *(float4*)(&AG[j * 68 + chb]) = acc;
        }
        if (first) {
            for (int j = w * 4; j < w * 4 + 4; ++j) {
                int nn = nbase + j;
                HH[j * 68 + lane] =
                    tv * enc_w[lane] + enc_w[(1 + nn) * DH + lane] + enc_b[lane];
            }
        } else {
            for (int j = w * 4; j < w * 4 + 4; ++j)
                HH[j * 68 + lane] = h[((size_t)rowbase + j) * DH + lane];
        }
    }
    __syncthreads();

    // ---- stage 1: agg = aggpre @ W2 + deg*b2 (wave w = quadrant nt=w) ----
    {
        float za[16];
        #pragma unroll
        for (int i = 0; i < 8; ++i) za[i] = AG[arow * 68 + k0 + i];
        #pragma unroll
        for (int i = 0; i < 8; ++i) za[8 + i] = AG[arow * 68 + 32 + k0 + i];
        Frag ga0 = split8(&za[0]), ga1 = split8(&za[8]);
        const uint4* PW2H = pack + (size_t)(l * 6 + 2) * 512;
        const uint4* PW2L = PW2H + LOB;
        float b2v = b2[w * 16 + (lane & 15)];
        f32x4 a;
        #pragma unroll
        for (int r = 0; r < 4; ++r)
            a[r] = (float)counts[nbase + kgrp * 4 + r] * b2v;
        a = mm3(ga0, PW2H[(w * 2 + 0) * 64 + lane], PW2L[(w * 2 + 0) * 64 + lane], a);
        a = mm3(ga1, PW2H[(w * 2 + 1) * 64 + lane], PW2L[(w * 2 + 1) * 64 + lane], a);
        #pragma unroll
        for (int r = 0; r < 4; ++r)
            ST[(kgrp * 4 + r) * 68 + w * 16 + (lane & 15)] = a[r];
    }
    __syncthreads();

    // ---- stage 2: z = silu([h, agg] @ U1 + ub1) -> AG ----
    {
        float hf[16];
        #pragma unroll
        for (int i = 0; i < 8; ++i) hf[i] = HH[arow * 68 + k0 + i];
        #pragma unroll
        for (int i = 0; i < 8; ++i) hf[8 + i] = HH[arow * 68 + 32 + k0 + i];
        Frag ha0 = split8(&hf[0]), ha1 = split8(&hf[8]);
        float ka[16];
        #pragma unroll
        for (int i = 0; i < 8; ++i) ka[i] = ST[arow * 68 + k0 + i];
        #pragma unroll
        for (int i = 0; i < 8; ++i) ka[8 + i] = ST[arow * 68 + 32 + k0 + i];
        Frag ka0 = split8(&ka[0]), ka1 = split8(&ka[8]);
        const uint4* PU1tH = pack + (size_t)(l * 6 + 3) * 512;
        const uint4* PU1bH = pack + (size_t)(l * 6 + 4) * 512;
        const uint4* PU1tL = PU1tH + LOB;
        const uint4* PU1bL = PU1bH + LOB;
        float bv = ub1[w * 16 + (lane & 15)];
        f32x4 a;
        #pragma unroll
        for (int r = 0; r < 4; ++r) a[r] = bv;
        a = mm3(ha0, PU1tH[(w * 2 + 0) * 64 + lane], PU1tL[(w * 2 + 0) * 64 + lane], a);
        a = mm3(ha1, PU1tH[(w * 2 + 1) * 64 + lane], PU1tL[(w * 2 + 1) * 64 + lane], a);
        a = mm3(ka0, PU1bH[(w * 2 + 0) * 64 + lane], PU1bL[(w * 2 + 0) * 64 + lane], a);
        a = mm3(ka1, PU1bH[(w * 2 + 1) * 64 + lane], PU1bL[(w * 2 + 1) * 64 + lane], a);
        __syncthreads();   // all reads of AG (ga) and ST (ka) complete above
        #pragma unroll
        for (int r = 0; r < 4; ++r)
            AG[(kgrp * 4 + r) * 68 + w * 16 + (lane & 15)] = silu_f(a[r]);
    }
    __syncthreads();

    // ---- stage 3: hn = h + z @ U2 + ub2 -> HH (+=) ----
    {
        float kz[16];
        #pragma unroll
        for (int i = 0; i < 8; ++i) kz[i] = AG[arow * 68 + k0 + i];
        #pragma unroll
        for (int i = 0; i < 8; ++i) kz[8 + i] = AG[arow * 68 + 32 + k0 + i];
        Frag kz0 = split8(&kz[0]), kz1 = split8(&kz[8]);
        const uint4* PU2H = pack + (size_t)(l * 6 + 5) * 512;
        const uint4* PU2L = PU2H + LOB;
        float bv = ub2[w * 16 + (lane & 15)];
        f32x4 a;
        #pragma unroll
        for (int r = 0; r < 4; ++r) a[r] = bv;
        a = mm3(kz0, PU2H[(w * 2 + 0) * 64 + lane], PU2L[(w * 2 + 0) * 64 + lane], a);
        a = mm3(kz1, PU2H[(w * 2 + 1) * 64 + lane], PU2L[(w * 2 + 1) * 64 + lane], a);
        #pragma unroll
        for (int r = 0; r < 4; ++r)
            HH[(kgrp * 4 + r) * 68 + w * 16 + (lane & 15)] += a[r];
    }
    __syncthreads();

    // ---- readout or next-layer projections ----
    if (last) {
        #pragma unroll
        for (int r = 0; r < 4; ++r) {
            int j = w * 4 + r;
            float v = HH[j * 68 + lane] * ro_w[lane];
            v += __shfl_xor(v, 1);  v += __shfl_xor(v, 2);
            v += __shfl_xor(v, 4);  v += __shfl_xor(v, 8);
            v += __shfl_xor(v, 16); v += __shfl_xor(v, 32);
            if (lane == 0) out[rowbase + j] = v + ro_b[0];
        }
        return;
    }
    // store h
    for (int j = w * 4; j < w * 4 + 4; ++j)
        h[((size_t)rowbase + j) * DH + lane] = HH[j * 68 + lane];
    // projections (quadrant w)
    {
        float hn[16];
        #pragma unroll
        for (int i = 0; i < 8; ++i) hn[i] = HH[arow * 68 + k0 + i];
        #pragma unroll
        for (int i = 0; i < 8; ++i) hn[8 + i] = HH[arow * 68 + 32 + k0 + i];
        Frag na0 = split8(&hn[0]), na1 = split8(&hn[8]);
        const uint4* PWtH = pack + (size_t)((l + 1) * 6 + 0) * 512;
        const uint4* PWbH = pack + (size_t)((l + 1) * 6 + 1) * 512;
        const uint4* PWtL = PWtH + LOB;
        const uint4* PWbL = PWbH + LOB;
        float b1v = b1n[w * 16 + (lane & 15)];
        f32x4 s; f32x4 d;
        #pragma unroll
        for (int r = 0; r < 4; ++r) { s[r] = 0.f; d[r] = b1v; }
        s = mm3(na0, PWtH[(w * 2 + 0) * 64 + lane], PWtL[(w * 2 + 0) * 64 + lane], s);
        s = mm3(na1, PWtH[(w * 2 + 1) * 64 + lane], PWtL[(w * 2 + 1) * 64 + lane], s);
        d = mm3(na0, PWbH[(w * 2 + 0) * 64 + lane], PWbL[(w * 2 + 0) * 64 + lane], d);
        d = mm3(na1, PWbH[(w * 2 + 1) * 64 + lane], PWbL[(w * 2 + 1) * 64 + lane], d);
        #pragma unroll
        for (int r = 0; r < 4; ++r) {
            int rr = rowbase + kgrp * 4 + r;
            hs_out[(size_t)rr * DH + w * 16 + (lane & 15)] = s[r];
            hd[(size_t)rr * DH + w * 16 + (lane & 15)] = d[r];
        }
    }
}

extern "C" void kernel_launch(void* const* d_in, const int* in_sizes, int n_in,
                              void* d_out, int out_size, void* d_ws, size_t ws_size,
                              hipStream_t stream) {
    const float* t      = (const float*)d_in[0];
    const int*   ei     = (const int*)d_in[1];
    const float* enc_w  = (const float*)d_in[2];
    const float* enc_b  = (const float*)d_in[3];
    const float* msg1_w = (const float*)d_in[4];
    const float* msg1_b = (const float*)d_in[5];
    const float* msg2_w = (const float*)d_in[6];
    const float* msg2_b = (const float*)d_in[7];
    const float* upd1_w = (const float*)d_in[8];
    const float* upd1_b = (const float*)d_in[9];
    const float* upd2_w = (const float*)d_in[10];
    const float* upd2_b = (const float*)d_in[11];
    const float* ro_w   = (const float*)d_in[12];
    const float* ro_b   = (const float*)d_in[13];
    float* out = (float*)d_out;

    const size_t HN = (size_t)TT * NN * DH;   // 4 Mi elements
    float* h    = (float*)d_ws;                     // 16 MB
    float* hs0  = h + HN;                           // 16 MB
    float* hs1  = hs0 + HN;                         // 16 MB
    float* hd   = hs1 + HN;                         // 16 MB
    uint4* pack = (uint4*)(hd + HN);                // 288 KB (hi+lo)
    int* counts  = (int*)(pack + 2 * LOB);
    int* offsets = counts + NN;
    int* ssrc    = offsets + NN + 1;
    float* E1s   = (float*)(ssrc + EE);             // 128 KB
    float* E1d   = E1s + NN * DH;                   // 128 KB
    float* e0sum = E1d + NN * DH;                   // 256 B

    setup_kernel<<<84, 512, 0, stream>>>(ei, msg1_w, msg2_w, upd1_w, upd2_w,
                                         enc_w, enc_b, msg1_b,
                                         pack, counts, offsets, ssrc,
                                         E1s, E1d, e0sum);

    for (int l = 0; l < 3; ++l) {
        int first = (l == 0), last = (l == 2);
        const float* hs_in = (l == 1) ? hs0 : hs1;   // l=0 unused, l=2 reads hs1
        float* hs_out      = (l == 0) ? hs0 : hs1;   // l=2 unused
        layer_kernel<<<TT * NN / 16, 256, 0, stream>>>(
            t, enc_w, enc_b, e0sum, E1s, E1d,
            h, hs_in, hs_out, hd,
            counts, offsets, ssrc, pack, l,
            msg2_b + (size_t)l * DH, upd1_b + (size_t)l * DH,
            upd2_b + (size_t)l * DH,
            last ? msg1_b : msg1_b + (size_t)(l + 1) * DH,
            ro_w, ro_b, out, first, last);
    }
}